// Round 13
// baseline (1050.658 us; speedup 1.0000x reference)
//
#include <hip/hip_runtime.h>
#include <hip/hip_fp16.h>

typedef _Float16 half8 __attribute__((ext_vector_type(8)));
typedef _Float16 half4 __attribute__((ext_vector_type(4)));
typedef float floatx4 __attribute__((ext_vector_type(4)));

#define PLANE 65536              // 16*16*256 fp16 elems per image
#define PK_ELEMS 589824          // 9*8*16*64*8 per layer
#define GUARD 4096               // 16 guard pixels * 256 ch each end of LDS plane

// ---------------- weight repack: fp32 -> fp16 MFMA A-fragment layout ----------------
// pack[layer][tap][ks][nt][lane][j] = W[co = nt*16+(lane&15)][ci = ks*32+(lane>>4)*8+j][tap]
// layer 3 = convT effective weight wt[ci][co][2-ky][2-kx].
__global__ void repack_kernel(const float* __restrict__ w2, const float* __restrict__ w3,
                              const float* __restrict__ w4, const float* __restrict__ wt,
                              _Float16* __restrict__ pk) {
    int t = blockIdx.x * 256 + threadIdx.x;     // 294912 total
    int l = t & 63;
    int idx = t >> 6;
    int nt = idx & 15; idx >>= 4;
    int ks = idx & 7;  idx >>= 3;               // idx in [0,36)
    int tap = idx % 9;
    int layer = idx / 9;
    int co = nt * 16 + (l & 15);
    int ci0 = ks * 32 + (l >> 4) * 8;
    const float* w = (layer == 0) ? w2 : (layer == 1) ? w3 : (layer == 2) ? w4 : wt;
    _Float16* dst = pk + (size_t)layer * PK_ELEMS + (((size_t)(tap * 8 + ks) * 16 + nt) * 64 + l) * 8;
    if (layer < 3) {
        for (int j = 0; j < 8; ++j)
            dst[j] = (_Float16)w[(co * 256 + (ci0 + j)) * 9 + tap];
    } else {
        int ky = tap / 3, kx = tap % 3;
        for (int j = 0; j < 8; ++j)
            dst[j] = (_Float16)w[((ci0 + j) * 256 + co) * 9 + (2 - ky) * 3 + (2 - kx)];
    }
}

// ---------------- conv1: 3->256, direct fp32, writes padded swizzled fp16 act ----------------
__global__ __launch_bounds__(1024, 4) void conv1_kernel(const float* __restrict__ x,
                                                        const float* __restrict__ w1,
                                                        const float* __restrict__ b1,
                                                        _Float16* __restrict__ act) {
    __shared__ float inl[3][16][16];
    __shared__ float lw[256 * 27];
    __shared__ float lb1[256];
    int n = blockIdx.x, tid = threadIdx.x;
    if (tid < 768) ((float*)inl)[tid] = 0.f;
    __syncthreads();
    for (int i = tid; i < 3 * 196; i += 1024) {
        int ci = i / 196, r = i % 196, y = r / 14, xx = r % 14;
        inl[ci][y + 1][xx + 1] = x[(size_t)n * 588 + i];
    }
    for (int i = tid; i < 256 * 27; i += 1024) lw[i] = w1[i];
    if (tid < 256) lb1[tid] = b1[tid];
    __syncthreads();
    int p = tid >> 2, q = tid & 3;
    int py = p >> 4, px = p & 15;
    _Float16* ga = act + (size_t)n * PLANE + p * 256;
    int sw = (p & 7) << 3;
    if (py == 0 || py == 15 || px == 0 || px == 15) {
        for (int ci = 0; ci < 64; ++ci) { int co = q + ci * 4; ga[co ^ sw] = (_Float16)0.f; }
    } else {
        float vin[27];
        #pragma unroll
        for (int ci = 0; ci < 3; ++ci)
            #pragma unroll
            for (int ky = 0; ky < 3; ++ky)
                #pragma unroll
                for (int kx = 0; kx < 3; ++kx)
                    vin[ci * 9 + ky * 3 + kx] = inl[ci][py - 1 + ky][px - 1 + kx];
        for (int ci = 0; ci < 64; ++ci) {
            int co = q + ci * 4;
            float acc = lb1[co];
            const float* wp = &lw[co * 27];
            #pragma unroll
            for (int k = 0; k < 27; ++k) acc += vin[k] * wp[k];
            ga[co ^ sw] = (_Float16)fmaxf(acc, 0.f);
        }
    }
}

// ---------------- fused: conv2..4 + convT + 1x1 + sigmoid, LDS-resident plane ----------------
// 768 threads = 12 waves (3/SIMD): cg = wid&3 (co-group of 4 nt), pg = wid>>2 (0..2).
// M-tile = one PADDED row (cols 0..15): row rr = pg+3*i+1, i<5; pg=2's i=4 tile is
// CLAMPED to row 13 (computed redundantly, writes guarded) so the hot loop is branch-free.
// ppix&7 == col&7 -> uniform 2-way LDS banking (free). Guard bands absorb edge taps.
// ACCUM_TAP = R12 ping-pong: half-tile B double-buffer (bA[3]/bB[2]) + A ping-pong (aP/aN).

#define INIT_ACC(BIASPTR)                                                        \
    {                                                                            \
        _Pragma("unroll")                                                        \
        for (int ni = 0; ni < 4; ++ni) {                                         \
            floatx4 bv;                                                          \
            _Pragma("unroll")                                                    \
            for (int reg = 0; reg < 4; ++reg)                                    \
                bv[reg] = (BIASPTR)[(cg * 4 + ni) * 16 + kg * 4 + reg];          \
            _Pragma("unroll")                                                    \
            for (int i = 0; i < 5; ++i) acc[i][ni] = bv;                         \
        }                                                                        \
    }

#define BURST3(AF, BF)                                                           \
    {                                                                            \
        _Pragma("unroll")                                                        \
        for (int j = 0; j < 3; ++j) {                                            \
            acc[j][0] = __builtin_amdgcn_mfma_f32_16x16x32_f16(AF[0], BF[j], acc[j][0], 0, 0, 0); \
            acc[j][1] = __builtin_amdgcn_mfma_f32_16x16x32_f16(AF[1], BF[j], acc[j][1], 0, 0, 0); \
            acc[j][2] = __builtin_amdgcn_mfma_f32_16x16x32_f16(AF[2], BF[j], acc[j][2], 0, 0, 0); \
            acc[j][3] = __builtin_amdgcn_mfma_f32_16x16x32_f16(AF[3], BF[j], acc[j][3], 0, 0, 0); \
        }                                                                        \
    }

#define BURST2(AF, BF)                                                           \
    {                                                                            \
        _Pragma("unroll")                                                        \
        for (int j = 0; j < 2; ++j) {                                            \
            acc[3 + j][0] = __builtin_amdgcn_mfma_f32_16x16x32_f16(AF[0], BF[j], acc[3 + j][0], 0, 0, 0); \
            acc[3 + j][1] = __builtin_amdgcn_mfma_f32_16x16x32_f16(AF[1], BF[j], acc[3 + j][1], 0, 0, 0); \
            acc[3 + j][2] = __builtin_amdgcn_mfma_f32_16x16x32_f16(AF[2], BF[j], acc[3 + j][2], 0, 0, 0); \
            acc[3 + j][3] = __builtin_amdgcn_mfma_f32_16x16x32_f16(AF[3], BF[j], acc[3 + j][3], 0, 0, 0); \
        }                                                                        \
    }

#define LOAD_B3(BF, KS)                                                          \
    {                                                                            \
        int kk_ = ((KS) * 4 + kg) << 3;                                          \
        _Pragma("unroll")                                                        \
        for (int j = 0; j < 3; ++j)                                              \
            BF[j] = *(const half8*)(plane + poff_[j] + (kk_ ^ swj_[j]));         \
    }

#define LOAD_B2(BF, KS)                                                          \
    {                                                                            \
        int kk_ = ((KS) * 4 + kg) << 3;                                          \
        _Pragma("unroll")                                                        \
        for (int j = 0; j < 2; ++j)                                              \
            BF[j] = *(const half8*)(plane + poff_[3 + j] + (kk_ ^ swj_[3 + j])); \
    }

#define LOAD_A(AF, KS)                                                           \
    {                                                                            \
        _Pragma("unroll")                                                        \
        for (int ni = 0; ni < 4; ++ni)                                           \
            AF[ni] = *(const half8*)(pkt_ + (((KS) * 16 + cg * 4 + ni) * 64 + lane) * 8); \
    }

#define ACCUM_TAP(PKT, DOFF)                                                     \
    {                                                                            \
        const _Float16* pkt_ = (PKT);                                            \
        int poff_[5], swj_[5];                                                   \
        _Pragma("unroll")                                                        \
        for (int j = 0; j < 5; ++j) {                                            \
            poff_[j] = (pp[j] + (DOFF)) * 256;                                   \
            swj_[j] = (poff_[j] >> 5) & 56;                                      \
        }                                                                        \
        half8 aP[4], aN[4], bA[3], bB[2];                                        \
        LOAD_A(aP, 0)                                                            \
        LOAD_B3(bA, 0)                                                           \
        _Pragma("clang loop unroll(disable)")                                    \
        for (int ks2 = 0; ks2 < 4; ++ks2) {                                      \
            int e = ks2 * 2, o = e + 1;                                          \
            LOAD_B2(bB, e)                                                       \
            LOAD_A(aN, o)                                                        \
            BURST3(aP, bA)                                                       \
            LOAD_B3(bA, o)                                                       \
            BURST2(aP, bB)                                                       \
            LOAD_B2(bB, o)                                                       \
            if (ks2 < 3) LOAD_A(aP, e + 2)                                       \
            BURST3(aN, bA)                                                       \
            if (ks2 < 3) LOAD_B3(bA, e + 2)                                      \
            BURST2(aN, bB)                                                       \
        }                                                                        \
    }

#define EPILOGUE(RY, RX)                                                         \
    {                                                                            \
        _Pragma("unroll")                                                        \
        for (int i = 0; i < 5; ++i) {                                            \
            float s0 = 0.f, s1 = 0.f, s2 = 0.f;                                  \
            _Pragma("unroll")                                                    \
            for (int ni = 0; ni < 4; ++ni) {                                     \
                int co0 = (cg * 4 + ni) * 16 + kg * 4;                           \
                _Pragma("unroll")                                                \
                for (int reg = 0; reg < 4; ++reg) {                              \
                    float v = fmaxf(acc[i][ni][reg], 0.f);                       \
                    s0 += v * w5l[co0 + reg];                                    \
                    s1 += v * w5l[256 + co0 + reg];                              \
                    s2 += v * w5l[512 + co0 + reg];                              \
                }                                                                \
            }                                                                    \
            s0 += __shfl_xor(s0, 16, 64); s0 += __shfl_xor(s0, 32, 64);          \
            s1 += __shfl_xor(s1, 16, 64); s1 += __shfl_xor(s1, 32, 64);          \
            s2 += __shfl_xor(s2, 16, 64); s2 += __shfl_xor(s2, 32, 64);          \
            if ((i < 4 || t4) && lane < 16 && colok) {                           \
                int yy = pg + 3 * i;                                             \
                int pix = (2 * yy + (RY)) * 28 + 2 * (col - 1) + (RX);           \
                atomicAdd(&o3[pix * 3 + 0], s0);                                 \
                atomicAdd(&o3[pix * 3 + 1], s1);                                 \
                atomicAdd(&o3[pix * 3 + 2], s2);                                 \
            }                                                                    \
        }                                                                        \
    }

__global__ __launch_bounds__(768, 3) void fused_kernel(const _Float16* __restrict__ act,
                                                       const _Float16* __restrict__ pk,
                                                       const float* __restrict__ b2,
                                                       const float* __restrict__ b3,
                                                       const float* __restrict__ b4,
                                                       const float* __restrict__ bt,
                                                       const float* __restrict__ w5,
                                                       const float* __restrict__ b5,
                                                       float* __restrict__ out) {
    __shared__ _Float16 plane[PLANE + 2 * GUARD];  // 144 KB: [guard16px | 256px | guard16px]
    __shared__ float o3[2352];                     // [pix][c] 1x1-conv accumulator
    __shared__ float w5l[768];                     // w5 staged for broadcast reads
    int n = blockIdx.x, tid = threadIdx.x;
    const _Float16* ga = act + (size_t)n * PLANE;
    // zero both guard bands (1024 uint4)
    for (int i = tid; i < 1024; i += 768) {
        int e = (i < 512) ? i : (i - 512) + (GUARD + PLANE) / 8;
        *(uint4*)(plane + e * 8) = uint4{0, 0, 0, 0};
    }
    for (int i = tid; i < 8192; i += 768)
        *(uint4*)(plane + GUARD + i * 8) = *(const uint4*)(ga + i * 8);
    for (int i = tid; i < 2352; i += 768) o3[i] = b5[i % 3];
    w5l[tid] = w5[tid];

    int lane = tid & 63;
    int wid = __builtin_amdgcn_readfirstlane(tid >> 6);   // wave-uniform in SGPR
    int cg = wid & 3, pg = wid >> 2;       // cg: 4 co-groups, pg: 3 row-groups
    int col = lane & 15, kg = lane >> 4;
    bool colok = (col >= 1 && col <= 14);
    bool t4 = (pg < 2);                    // 5th tile real only for pg<2

    // M-tile = padded row rr = pg + 3*i + 1 (i<5); pg=2,i=4 clamped to row 13 (dup work).
    int pp[5];
    #pragma unroll
    for (int i = 0; i < 5; ++i) {
        int rr = pg + 3 * i + 1; if (rr > 14) rr = 13;
        pp[i] = rr * 16 + col + 16;
    }
    __syncthreads();

    floatx4 acc[5][4];

    // ---- conv2..conv4: plane -> plane ----
    for (int L = 0; L < 3; ++L) {
        const _Float16* pkL = pk + (size_t)L * PK_ELEMS;
        const float* bias = (L == 0) ? b2 : (L == 1) ? b3 : b4;
        INIT_ACC(bias)
        for (int tap = 0; tap < 9; ++tap) {
            int doff = (tap / 3) * 16 + (tap % 3) - 17;
            ACCUM_TAP(pkL + (size_t)tap * 65536, doff)
        }
        __syncthreads();   // all reads of plane done
        #pragma unroll
        for (int i = 0; i < 5; ++i) {
            if ((i < 4 || t4) && colok) {
                int ppix = pp[i];
                int sw = (ppix & 7) << 3;
                #pragma unroll
                for (int ni = 0; ni < 4; ++ni) {
                    int co0 = (cg * 4 + ni) * 16 + kg * 4;
                    half4 h;
                    #pragma unroll
                    for (int reg = 0; reg < 4; ++reg) h[reg] = (_Float16)fmaxf(acc[i][ni][reg], 0.f);
                    *(half4*)(plane + ppix * 256 + (co0 ^ sw)) = h;
                }
            }
        }
        __syncthreads();   // plane updated for next layer
    }

    // ---- convT (4 parity classes, bt folded into init) + ReLU + 1x1 into o3 ----
    const _Float16* pkT = pk + (size_t)3 * PK_ELEMS;
    // class (ry=0,rx=0): tap 4
    INIT_ACC(bt)
    ACCUM_TAP(pkT + 4 * 65536, 0)
    EPILOGUE(0, 0)
    // class (0,1): taps 3 (+0), 5 (+1)
    INIT_ACC(bt)
    ACCUM_TAP(pkT + 3 * 65536, 0)
    ACCUM_TAP(pkT + 5 * 65536, 1)
    EPILOGUE(0, 1)
    // class (1,0): taps 1 (+0), 7 (+16)
    INIT_ACC(bt)
    ACCUM_TAP(pkT + 1 * 65536, 0)
    ACCUM_TAP(pkT + 7 * 65536, 16)
    EPILOGUE(1, 0)
    // class (1,1): taps 0 (+0), 2 (+1), 6 (+16), 8 (+17)
    INIT_ACC(bt)
    ACCUM_TAP(pkT + 0 * 65536, 0)
    ACCUM_TAP(pkT + 2 * 65536, 1)
    ACCUM_TAP(pkT + 6 * 65536, 16)
    ACCUM_TAP(pkT + 8 * 65536, 17)
    EPILOGUE(1, 1)

    __syncthreads();
    size_t ob = (size_t)n * 2352;
    for (int i = tid; i < 2352; i += 768) {
        int pix = i / 3, c = i % 3;
        float v = o3[i];
        out[ob + (size_t)c * 784 + pix] = 1.f / (1.f + __expf(-v));
    }
}

extern "C" void kernel_launch(void* const* d_in, const int* in_sizes, int n_in,
                              void* d_out, int out_size, void* d_ws, size_t ws_size,
                              hipStream_t stream) {
    const float* x  = (const float*)d_in[0];
    const float* w1 = (const float*)d_in[1];
    const float* b1 = (const float*)d_in[2];
    const float* w2 = (const float*)d_in[3];
    const float* b2 = (const float*)d_in[4];
    const float* w3 = (const float*)d_in[5];
    const float* b3 = (const float*)d_in[6];
    const float* w4 = (const float*)d_in[7];
    const float* b4 = (const float*)d_in[8];
    const float* wt = (const float*)d_in[9];
    const float* bt = (const float*)d_in[10];
    const float* w5 = (const float*)d_in[11];
    const float* b5 = (const float*)d_in[12];

    size_t need = ((size_t)1024 * PLANE + 4 * (size_t)PK_ELEMS) * sizeof(_Float16);
    if (ws_size < need) return;  // workspace too small — cannot run

    _Float16* act = (_Float16*)d_ws;
    _Float16* pk  = act + (size_t)1024 * PLANE;

    repack_kernel<<<1152, 256, 0, stream>>>(w2, w3, w4, wt, pk);
    conv1_kernel<<<1024, 1024, 0, stream>>>(x, w1, b1, act);
    fused_kernel<<<1024, 768, 0, stream>>>(act, pk, b2, b3, b4, bt, w5, b5, (float*)d_out);
}

// Round 14
// 888.130 us; speedup vs baseline: 1.1830x; 1.1830x over previous
//
#include <hip/hip_runtime.h>
#include <hip/hip_fp16.h>

typedef _Float16 half8 __attribute__((ext_vector_type(8)));
typedef _Float16 half4 __attribute__((ext_vector_type(4)));
typedef float floatx4 __attribute__((ext_vector_type(4)));

#define PLANE 65536              // 16*16*256 fp16 elems per image
#define PK_ELEMS 589824          // 9*8*16*64*8 per layer

// ---------------- weight repack: fp32 -> fp16 MFMA A-fragment layout ----------------
// pack[layer][tap][ks][nt][lane][j] = W[co = nt*16+(lane&15)][ci = ks*32+(lane>>4)*8+j][tap]
// layer 3 = convT effective weight wt[ci][co][2-ky][2-kx].
__global__ void repack_kernel(const float* __restrict__ w2, const float* __restrict__ w3,
                              const float* __restrict__ w4, const float* __restrict__ wt,
                              _Float16* __restrict__ pk) {
    int t = blockIdx.x * 256 + threadIdx.x;     // 294912 total
    int l = t & 63;
    int idx = t >> 6;
    int nt = idx & 15; idx >>= 4;
    int ks = idx & 7;  idx >>= 3;               // idx in [0,36)
    int tap = idx % 9;
    int layer = idx / 9;
    int co = nt * 16 + (l & 15);
    int ci0 = ks * 32 + (l >> 4) * 8;
    const float* w = (layer == 0) ? w2 : (layer == 1) ? w3 : (layer == 2) ? w4 : wt;
    _Float16* dst = pk + (size_t)layer * PK_ELEMS + (((size_t)(tap * 8 + ks) * 16 + nt) * 64 + l) * 8;
    if (layer < 3) {
        for (int j = 0; j < 8; ++j)
            dst[j] = (_Float16)w[(co * 256 + (ci0 + j)) * 9 + tap];
    } else {
        int ky = tap / 3, kx = tap % 3;
        for (int j = 0; j < 8; ++j)
            dst[j] = (_Float16)w[((ci0 + j) * 256 + co) * 9 + (2 - ky) * 3 + (2 - kx)];
    }
}

// ---------------- conv1: 3->256, direct fp32, writes padded swizzled fp16 act ----------------
__global__ __launch_bounds__(1024, 4) void conv1_kernel(const float* __restrict__ x,
                                                        const float* __restrict__ w1,
                                                        const float* __restrict__ b1,
                                                        _Float16* __restrict__ act) {
    __shared__ float inl[3][16][16];
    __shared__ float lw[256 * 27];
    __shared__ float lb1[256];
    int n = blockIdx.x, tid = threadIdx.x;
    if (tid < 768) ((float*)inl)[tid] = 0.f;
    __syncthreads();
    for (int i = tid; i < 3 * 196; i += 1024) {
        int ci = i / 196, r = i % 196, y = r / 14, xx = r % 14;
        inl[ci][y + 1][xx + 1] = x[(size_t)n * 588 + i];
    }
    for (int i = tid; i < 256 * 27; i += 1024) lw[i] = w1[i];
    if (tid < 256) lb1[tid] = b1[tid];
    __syncthreads();
    int p = tid >> 2, q = tid & 3;
    int py = p >> 4, px = p & 15;
    _Float16* ga = act + (size_t)n * PLANE + p * 256;
    int sw = (p & 7) << 3;
    if (py == 0 || py == 15 || px == 0 || px == 15) {
        for (int ci = 0; ci < 64; ++ci) { int co = q + ci * 4; ga[co ^ sw] = (_Float16)0.f; }
    } else {
        float vin[27];
        #pragma unroll
        for (int ci = 0; ci < 3; ++ci)
            #pragma unroll
            for (int ky = 0; ky < 3; ++ky)
                #pragma unroll
                for (int kx = 0; kx < 3; ++kx)
                    vin[ci * 9 + ky * 3 + kx] = inl[ci][py - 1 + ky][px - 1 + kx];
        for (int ci = 0; ci < 64; ++ci) {
            int co = q + ci * 4;
            float acc = lb1[co];
            const float* wp = &lw[co * 27];
            #pragma unroll
            for (int k = 0; k < 27; ++k) acc += vin[k] * wp[k];
            ga[co ^ sw] = (_Float16)fmaxf(acc, 0.f);
        }
    }
}

// ---------------- fused: conv2..4 + convT + 1x1 + sigmoid, LDS-resident plane ----------------
// 512 threads = 8 waves (2/SIMD): cg = wid>>1 (co-group of 4 nt), pg = wid&1 (rows pg,pg+2,..).
// M-tile = one image row. Swapped-operand MFMA: D[row=co][col=x].
// ACCUM_TAP: half-tile B ping-pong (bA[4]/bB[3]) + named-buffer A ping-pong (aP/aN),
// manual 2-ks body. s_setprio(1) wraps each MFMA burst (T5): no intra-tap barriers ->
// the 2 waves/SIMD drift into {load vs MFMA} roles; priority keeps the matrix pipe fed.

#define INIT_ACC(BIASPTR)                                                        \
    {                                                                            \
        _Pragma("unroll")                                                        \
        for (int ni = 0; ni < 4; ++ni) {                                         \
            floatx4 bv;                                                          \
            _Pragma("unroll")                                                    \
            for (int reg = 0; reg < 4; ++reg)                                    \
                bv[reg] = (BIASPTR)[(cg * 4 + ni) * 16 + kg * 4 + reg];          \
            _Pragma("unroll")                                                    \
            for (int i = 0; i < 7; ++i) acc[i][ni] = bv;                         \
        }                                                                        \
    }

#define BURST4(AF, BF)                                                           \
    {                                                                            \
        __builtin_amdgcn_s_setprio(1);                                           \
        _Pragma("unroll")                                                        \
        for (int j = 0; j < 4; ++j) {                                            \
            acc[j][0] = __builtin_amdgcn_mfma_f32_16x16x32_f16(AF[0], BF[j], acc[j][0], 0, 0, 0); \
            acc[j][1] = __builtin_amdgcn_mfma_f32_16x16x32_f16(AF[1], BF[j], acc[j][1], 0, 0, 0); \
            acc[j][2] = __builtin_amdgcn_mfma_f32_16x16x32_f16(AF[2], BF[j], acc[j][2], 0, 0, 0); \
            acc[j][3] = __builtin_amdgcn_mfma_f32_16x16x32_f16(AF[3], BF[j], acc[j][3], 0, 0, 0); \
        }                                                                        \
        __builtin_amdgcn_s_setprio(0);                                           \
    }

#define BURST3(AF, BF)                                                           \
    {                                                                            \
        __builtin_amdgcn_s_setprio(1);                                           \
        _Pragma("unroll")                                                        \
        for (int j = 0; j < 3; ++j) {                                            \
            acc[4 + j][0] = __builtin_amdgcn_mfma_f32_16x16x32_f16(AF[0], BF[j], acc[4 + j][0], 0, 0, 0); \
            acc[4 + j][1] = __builtin_amdgcn_mfma_f32_16x16x32_f16(AF[1], BF[j], acc[4 + j][1], 0, 0, 0); \
            acc[4 + j][2] = __builtin_amdgcn_mfma_f32_16x16x32_f16(AF[2], BF[j], acc[4 + j][2], 0, 0, 0); \
            acc[4 + j][3] = __builtin_amdgcn_mfma_f32_16x16x32_f16(AF[3], BF[j], acc[4 + j][3], 0, 0, 0); \
        }                                                                        \
        __builtin_amdgcn_s_setprio(0);                                           \
    }

#define LOAD_B4(BF, KS)                                                          \
    {                                                                            \
        int kk_ = ((KS) * 4 + kg) << 3;                                          \
        _Pragma("unroll")                                                        \
        for (int j = 0; j < 4; ++j)                                              \
            BF[j] = *(const half8*)(plane + poff_[j] + (kk_ ^ swj_[j]));         \
    }

#define LOAD_B3(BF, KS)                                                          \
    {                                                                            \
        int kk_ = ((KS) * 4 + kg) << 3;                                          \
        _Pragma("unroll")                                                        \
        for (int j = 0; j < 3; ++j)                                              \
            BF[j] = *(const half8*)(plane + poff_[4 + j] + (kk_ ^ swj_[4 + j])); \
    }

#define LOAD_A(AF, KS)                                                           \
    {                                                                            \
        _Pragma("unroll")                                                        \
        for (int ni = 0; ni < 4; ++ni)                                           \
            AF[ni] = *(const half8*)(pkt_ + (((KS) * 16 + cg * 4 + ni) * 64 + lane) * 8); \
    }

#define ACCUM_TAP(PKT, DOFF)                                                     \
    {                                                                            \
        const _Float16* pkt_ = (PKT);                                            \
        int poff_[7], swj_[7];                                                   \
        _Pragma("unroll")                                                        \
        for (int j = 0; j < 7; ++j) {                                            \
            poff_[j] = (pp[j] + (DOFF)) * 256;                                   \
            swj_[j] = (poff_[j] >> 5) & 56;                                      \
        }                                                                        \
        half8 aP[4], aN[4], bA[4], bB[3];                                        \
        LOAD_A(aP, 0)                                                            \
        LOAD_B4(bA, 0)                                                           \
        _Pragma("clang loop unroll(disable)")                                    \
        for (int ks2 = 0; ks2 < 4; ++ks2) {                                      \
            int e = ks2 * 2, o = e + 1;                                          \
            LOAD_B3(bB, e)                                                       \
            LOAD_A(aN, o)                                                        \
            BURST4(aP, bA)                                                       \
            LOAD_B4(bA, o)                                                       \
            BURST3(aP, bB)                                                       \
            LOAD_B3(bB, o)                                                       \
            if (ks2 < 3) LOAD_A(aP, e + 2)                                       \
            BURST4(aN, bA)                                                       \
            if (ks2 < 3) LOAD_B4(bA, e + 2)                                      \
            BURST3(aN, bB)                                                       \
        }                                                                        \
    }

#define EPILOGUE(RY, RX)                                                         \
    {                                                                            \
        _Pragma("unroll")                                                        \
        for (int i = 0; i < 7; ++i) {                                            \
            float s0 = 0.f, s1 = 0.f, s2 = 0.f;                                  \
            _Pragma("unroll")                                                    \
            for (int ni = 0; ni < 4; ++ni) {                                     \
                int co0 = (cg * 4 + ni) * 16 + kg * 4;                           \
                _Pragma("unroll")                                                \
                for (int reg = 0; reg < 4; ++reg) {                              \
                    float v = fmaxf(acc[i][ni][reg], 0.f);                       \
                    s0 += v * w5l[co0 + reg];                                    \
                    s1 += v * w5l[256 + co0 + reg];                              \
                    s2 += v * w5l[512 + co0 + reg];                              \
                }                                                                \
            }                                                                    \
            s0 += __shfl_xor(s0, 16, 64); s0 += __shfl_xor(s0, 32, 64);          \
            s1 += __shfl_xor(s1, 16, 64); s1 += __shfl_xor(s1, 32, 64);          \
            s2 += __shfl_xor(s2, 16, 64); s2 += __shfl_xor(s2, 32, 64);          \
            if (lane < 14) {                                                     \
                int pt_ = pg + 2 * i;                                            \
                int pix = (2 * pt_ + (RY)) * 28 + 2 * lane + (RX);               \
                atomicAdd(&o3[pix * 3 + 0], s0);                                 \
                atomicAdd(&o3[pix * 3 + 1], s1);                                 \
                atomicAdd(&o3[pix * 3 + 2], s2);                                 \
            }                                                                    \
        }                                                                        \
    }

__global__ __launch_bounds__(512, 2) void fused_kernel(const _Float16* __restrict__ act,
                                                       const _Float16* __restrict__ pk,
                                                       const float* __restrict__ b2,
                                                       const float* __restrict__ b3,
                                                       const float* __restrict__ b4,
                                                       const float* __restrict__ bt,
                                                       const float* __restrict__ w5,
                                                       const float* __restrict__ b5,
                                                       float* __restrict__ out) {
    __shared__ _Float16 plane[PLANE];   // 128 KB, resident across all layers
    __shared__ float o3[2352];          // [pix][c] 1x1-conv accumulator
    __shared__ float w5l[768];          // w5 staged for broadcast reads
    int n = blockIdx.x, tid = threadIdx.x;
    const _Float16* ga = act + (size_t)n * PLANE;
    #pragma unroll
    for (int i = 0; i < 16; ++i)
        *(uint4*)(plane + (i * 512 + tid) * 8) = *(const uint4*)(ga + (i * 512 + tid) * 8);
    for (int i = tid; i < 2352; i += 512) o3[i] = b5[i % 3];
    for (int i = tid; i < 768; i += 512) w5l[i] = w5[i];

    int lane = tid & 63;
    int wid = __builtin_amdgcn_readfirstlane(tid >> 6);   // wave-uniform in SGPR
    int cg = wid >> 1, pg = wid & 1;
    int col = lane & 15, kg = lane >> 4;

    // M-tile = image row pt = pg + 2*i (i<7): pixel (y=pt, x=col), 14 valid cols.
    int pp[7];
    {
        int xc = (col < 14) ? col : 13;   // clamp invalid lanes to a safe in-bounds pixel
        #pragma unroll
        for (int i = 0; i < 7; ++i) pp[i] = (pg + 2 * i + 1) * 16 + xc + 1;
    }
    bool colok = (col < 14);
    __syncthreads();

    floatx4 acc[7][4];

    // ---- conv2..conv4: plane -> plane ----
    for (int L = 0; L < 3; ++L) {
        const _Float16* pkL = pk + (size_t)L * PK_ELEMS;
        const float* bias = (L == 0) ? b2 : (L == 1) ? b3 : b4;
        INIT_ACC(bias)
        for (int tap = 0; tap < 9; ++tap) {
            int doff = (tap / 3) * 16 + (tap % 3) - 17;
            ACCUM_TAP(pkL + (size_t)tap * 65536, doff)
        }
        __syncthreads();   // all reads of plane done
        #pragma unroll
        for (int i = 0; i < 7; ++i) {
            int ppix = pp[i];
            int sw = (ppix & 7) << 3;
            if (colok) {
                #pragma unroll
                for (int ni = 0; ni < 4; ++ni) {
                    int co0 = (cg * 4 + ni) * 16 + kg * 4;
                    half4 h;
                    #pragma unroll
                    for (int reg = 0; reg < 4; ++reg) h[reg] = (_Float16)fmaxf(acc[i][ni][reg], 0.f);
                    *(half4*)(plane + ppix * 256 + (co0 ^ sw)) = h;
                }
            }
        }
        __syncthreads();   // plane updated for next layer
    }

    // ---- convT (4 parity classes, bt folded into init) + ReLU + 1x1 into o3 ----
    const _Float16* pkT = pk + (size_t)3 * PK_ELEMS;
    // class (ry=0,rx=0): tap 4
    INIT_ACC(bt)
    ACCUM_TAP(pkT + 4 * 65536, 0)
    EPILOGUE(0, 0)
    // class (0,1): taps 3 (+0), 5 (+1)
    INIT_ACC(bt)
    ACCUM_TAP(pkT + 3 * 65536, 0)
    ACCUM_TAP(pkT + 5 * 65536, 1)
    EPILOGUE(0, 1)
    // class (1,0): taps 1 (+0), 7 (+16)
    INIT_ACC(bt)
    ACCUM_TAP(pkT + 1 * 65536, 0)
    ACCUM_TAP(pkT + 7 * 65536, 16)
    EPILOGUE(1, 0)
    // class (1,1): taps 0 (+0), 2 (+1), 6 (+16), 8 (+17)
    INIT_ACC(bt)
    ACCUM_TAP(pkT + 0 * 65536, 0)
    ACCUM_TAP(pkT + 2 * 65536, 1)
    ACCUM_TAP(pkT + 6 * 65536, 16)
    ACCUM_TAP(pkT + 8 * 65536, 17)
    EPILOGUE(1, 1)

    __syncthreads();
    size_t ob = (size_t)n * 2352;
    for (int i = tid; i < 2352; i += 512) {
        int pix = i / 3, c = i % 3;
        float v = o3[i];
        out[ob + (size_t)c * 784 + pix] = 1.f / (1.f + __expf(-v));
    }
}

extern "C" void kernel_launch(void* const* d_in, const int* in_sizes, int n_in,
                              void* d_out, int out_size, void* d_ws, size_t ws_size,
                              hipStream_t stream) {
    const float* x  = (const float*)d_in[0];
    const float* w1 = (const float*)d_in[1];
    const float* b1 = (const float*)d_in[2];
    const float* w2 = (const float*)d_in[3];
    const float* b2 = (const float*)d_in[4];
    const float* w3 = (const float*)d_in[5];
    const float* b3 = (const float*)d_in[6];
    const float* w4 = (const float*)d_in[7];
    const float* b4 = (const float*)d_in[8];
    const float* wt = (const float*)d_in[9];
    const float* bt = (const float*)d_in[10];
    const float* w5 = (const float*)d_in[11];
    const float* b5 = (const float*)d_in[12];

    size_t need = ((size_t)1024 * PLANE + 4 * (size_t)PK_ELEMS) * sizeof(_Float16);
    if (ws_size < need) return;  // workspace too small — cannot run

    _Float16* act = (_Float16*)d_ws;
    _Float16* pk  = act + (size_t)1024 * PLANE;

    repack_kernel<<<1152, 256, 0, stream>>>(w2, w3, w4, wt, pk);
    conv1_kernel<<<1024, 1024, 0, stream>>>(x, w1, b1, act);
    fused_kernel<<<1024, 512, 0, stream>>>(act, pk, b2, b3, b4, bt, w5, b5, (float*)d_out);
}